// Round 5
// baseline (68.815 us; speedup 1.0000x reference)
//
#include <hip/hip_runtime.h>

// VQ nearest-codebook: x [16,64,64,64] NCHW fp32, emb [512,64] fp32.
// out = concat(one_hot [65536,512] f32, quantized [16,64,64,64] f32).
//
// Round-5: WAVE SPECIALIZATION. vmcnt is per-wave & in-order, so the 128 MB
// one-hot zero stream lives in dedicated writer waves (starts at t=0, HBM
// write-bound), while compute waves keep a store-free vmcnt queue: B-frags
// read straight from the frag-ordered L2-resident bf16 codebook (prep
// kernel), 3-pass split-bf16 MFMA, in-reg top-2, fp64 tie refine, quant
// writes. One barrier hands indices to writer waves for the 1.0 scatter
// (same wave that wrote the zeros => ordering guaranteed by the barrier's
// vmcnt(0) drain + program order).

constexpr int D    = 64;
constexpr int K    = 512;
constexpr int N    = 65536;
constexpr int HW   = 4096;
constexpr int TPB  = 256;
constexpr int PIXB = 64;             // pixels per block (32 per compute wave)
constexpr int NTILE = K / 16;        // 32 MFMA code tiles

typedef __attribute__((ext_vector_type(8))) short bf16x8;
typedef __attribute__((ext_vector_type(4))) short short4v;
typedef __attribute__((ext_vector_type(4))) float f32x4;

__device__ inline unsigned short f2bf(float f) {           // RNE f32->bf16
    unsigned u = __builtin_bit_cast(unsigned, f);
    unsigned r = u + 0x7fffu + ((u >> 16) & 1u);
    return (unsigned short)(r >> 16);
}
__device__ inline float bf2f(unsigned short h) {
    unsigned u = ((unsigned)h) << 16;
    return __builtin_bit_cast(float, u);
}

__device__ inline void top2_upd(float s, int code, float& bs, float& ss, int& bi, int& si) {
    bool c1 = s < bs;
    bool c2 = s < ss;
    ss = c1 ? bs : (c2 ? s : ss);
    si = c1 ? bi : (c2 ? code : si);
    bs = c1 ? s : bs;
    bi = c1 ? code : bi;
}
__device__ inline void top2_ins(float os, int oi, float& bs, float& ss, int& bi, int& si) {
    bool c1 = (os < bs) || (os == bs && oi < bi);
    bool c2 = (os < ss) || (os == ss && oi < si);
    ss = c1 ? bs : (c2 ? os : ss);
    si = c1 ? bi : (c2 ? oi : si);
    bs = c1 ? os : bs;
    bi = c1 ? oi : bi;
}

// ---------------- prep: emb -> frag-ordered hi/lo bf16 + e_sq ----------------
// ebuf layout (shorts): chunk*16384 + sec*4096 + tile*512 + cl*32 + g*8 + j
//   sec: 0=hi dims 0..31, 1=hi dims 32..63, 2=lo dims 0..31, 3=lo dims 32..63
// => a wave's fragment load (cl,g varying over lanes) is 1KB CONTIGUOUS.
__global__ __launch_bounds__(TPB) void vq_prep(
    const float* __restrict__ emb, short* __restrict__ ebuf, float* __restrict__ esq)
{
    const int t    = blockIdx.x * TPB + threadIdx.x;   // 8192 threads
    const int code = t >> 4;
    const int q    = t & 15;
    const int d0   = q * 4;
    float4 f = ((const float4*)emb)[t];
    unsigned short h0 = f2bf(f.x), h1 = f2bf(f.y), h2 = f2bf(f.z), h3 = f2bf(f.w);
    short4v hv = { (short)h0, (short)h1, (short)h2, (short)h3 };
    short4v lv = { (short)f2bf(f.x - bf2f(h0)), (short)f2bf(f.y - bf2f(h1)),
                   (short)f2bf(f.z - bf2f(h2)), (short)f2bf(f.w - bf2f(h3)) };
    const int chunk = code >> 7, cc = code & 127, tile = cc >> 4, cl = cc & 15;
    const int g = (d0 >> 3) & 3, j0 = d0 & 7, secH = (d0 >= 32) ? 1 : 0;
    const int base = chunk * 16384 + tile * 512 + cl * 32 + g * 8 + j0;
    *(short4v*)&ebuf[base + secH * 4096]       = hv;
    *(short4v*)&ebuf[base + (2 + secH) * 4096] = lv;
    float pe = f.x * f.x + f.y * f.y + f.z * f.z + f.w * f.w;
    pe += __shfl_xor(pe, 1);
    pe += __shfl_xor(pe, 2);
    pe += __shfl_xor(pe, 4);
    pe += __shfl_xor(pe, 8);
    if (q == 0) esq[code] = pe;
}

// ---------------- main ----------------
__global__ __launch_bounds__(TPB, 4) void vq_main(
    const float* __restrict__ x, const float* __restrict__ emb,
    const short* __restrict__ ebuf, const float* __restrict__ esq,
    float* __restrict__ enc, float* __restrict__ quant)
{
    __shared__ float s_bs[PIXB], s_ss[PIXB];
    __shared__ int   s_bi[PIXB], s_si[PIXB], s_idx[PIXB];

    const int tid  = threadIdx.x;
    const int lane = tid & 63;
    const int wave = __builtin_amdgcn_readfirstlane(tid >> 6);

    const int pixbase = blockIdx.x * PIXB;
    const int b   = pixbase >> 12;
    const int hw0 = pixbase & (HW - 1);
    const float* xb = x + (size_t)b * D * HW;

    if (wave < 2) {
        // ================= COMPUTE WAVES (store-free until quant) =================
        const int g    = lane >> 4;
        const int cl   = lane & 15;
        const int wloc = wave * 32;                 // this wave's 32 pixels

        // ---- x loads for two A-tiles (coalesced 64B segments) ----
        float xv0[16], xv1[16];
        #pragma unroll
        for (int j = 0; j < 8; ++j) {
            const size_t o0 = (size_t)(g * 8 + j) * HW + hw0 + wloc + cl;
            const size_t o1 = (size_t)(32 + g * 8 + j) * HW + hw0 + wloc + cl;
            xv0[j]     = xb[o0];       xv0[8 + j] = xb[o1];
            xv1[j]     = xb[o0 + 16];  xv1[8 + j] = xb[o1 + 16];
        }

        // ---- pack A fragments hi/lo ----
        bf16x8 a0h0, a0h1, a0l0, a0l1, a1h0, a1h1, a1l0, a1l1;
        #pragma unroll
        for (int j = 0; j < 8; ++j) {
            unsigned short h;
            h = f2bf(xv0[j]);     a0h0[j] = (short)h; a0l0[j] = (short)f2bf(xv0[j]     - bf2f(h));
            h = f2bf(xv0[8 + j]); a0h1[j] = (short)h; a0l1[j] = (short)f2bf(xv0[8 + j] - bf2f(h));
            h = f2bf(xv1[j]);     a1h0[j] = (short)h; a1l0[j] = (short)f2bf(xv1[j]     - bf2f(h));
            h = f2bf(xv1[8 + j]); a1h1[j] = (short)h; a1l1[j] = (short)f2bf(xv1[8 + j] - bf2f(h));
        }

        float bs0[4], ss0[4], bs1[4], ss1[4];
        int   bi0[4], si0[4], bi1[4], si1[4];
        #pragma unroll
        for (int r = 0; r < 4; ++r) {
            bs0[r] = ss0[r] = bs1[r] = ss1[r] = 3.4e38f;
            bi0[r] = si0[r] = bi1[r] = si1[r] = 0x7fffffff;
        }

        // ---- 32 code tiles; B-frags = contiguous 1KB loads from L2 codebook ----
        const bf16x8* gB = (const bf16x8*)ebuf;     // bf16x8 units (16B)
        #pragma unroll 2
        for (int t = 0; t < NTILE; ++t) {
            const int base8 = (t >> 3) * 2048 + (t & 7) * 64 + cl * 4 + g;
            bf16x8 bh0 = gB[base8];
            bf16x8 bh1 = gB[base8 + 512];
            bf16x8 bl0 = gB[base8 + 1024];
            bf16x8 bl1 = gB[base8 + 1536];
            const float eq = esq[t * 16 + cl];
            f32x4 c0 = {0.f, 0.f, 0.f, 0.f};
            f32x4 c1 = {0.f, 0.f, 0.f, 0.f};
            c0 = __builtin_amdgcn_mfma_f32_16x16x32_bf16(a0h0, bh0, c0, 0, 0, 0);
            c1 = __builtin_amdgcn_mfma_f32_16x16x32_bf16(a1h0, bh0, c1, 0, 0, 0);
            c0 = __builtin_amdgcn_mfma_f32_16x16x32_bf16(a0h1, bh1, c0, 0, 0, 0);
            c1 = __builtin_amdgcn_mfma_f32_16x16x32_bf16(a1h1, bh1, c1, 0, 0, 0);
            c0 = __builtin_amdgcn_mfma_f32_16x16x32_bf16(a0l0, bh0, c0, 0, 0, 0);
            c1 = __builtin_amdgcn_mfma_f32_16x16x32_bf16(a1l0, bh0, c1, 0, 0, 0);
            c0 = __builtin_amdgcn_mfma_f32_16x16x32_bf16(a0l1, bh1, c0, 0, 0, 0);
            c1 = __builtin_amdgcn_mfma_f32_16x16x32_bf16(a1l1, bh1, c1, 0, 0, 0);
            c0 = __builtin_amdgcn_mfma_f32_16x16x32_bf16(a0h0, bl0, c0, 0, 0, 0);
            c1 = __builtin_amdgcn_mfma_f32_16x16x32_bf16(a1h0, bl0, c1, 0, 0, 0);
            c0 = __builtin_amdgcn_mfma_f32_16x16x32_bf16(a0h1, bl1, c0, 0, 0, 0);
            c1 = __builtin_amdgcn_mfma_f32_16x16x32_bf16(a1h1, bl1, c1, 0, 0, 0);
            const int kcode = t * 16 + cl;
            #pragma unroll
            for (int r = 0; r < 4; ++r) {
                top2_upd(fmaf(-2.0f, c0[r], eq), kcode, bs0[r], ss0[r], bi0[r], si0[r]);
                top2_upd(fmaf(-2.0f, c1[r], eq), kcode, bs1[r], ss1[r], bi1[r], si1[r]);
            }
        }

        // ---- cross-lane top-2 merge (over cl within each g-group) ----
        #pragma unroll
        for (int r = 0; r < 4; ++r) {
            for (int m = 1; m <= 8; m <<= 1) {
                float obs, oss; int obi, osi;
                obs = __shfl_xor(bs0[r], m); obi = __shfl_xor(bi0[r], m);
                oss = __shfl_xor(ss0[r], m); osi = __shfl_xor(si0[r], m);
                top2_ins(obs, obi, bs0[r], ss0[r], bi0[r], si0[r]);
                top2_ins(oss, osi, bs0[r], ss0[r], bi0[r], si0[r]);
                obs = __shfl_xor(bs1[r], m); obi = __shfl_xor(bi1[r], m);
                oss = __shfl_xor(ss1[r], m); osi = __shfl_xor(si1[r], m);
                top2_ins(obs, obi, bs1[r], ss1[r], bi1[r], si1[r]);
                top2_ins(oss, osi, bs1[r], ss1[r], bi1[r], si1[r]);
            }
        }
        if (cl == 0) {
            #pragma unroll
            for (int r = 0; r < 4; ++r) {
                const int p0 = wloc + g * 4 + r;      // C/D row = (lane>>4)*4+reg
                s_bs[p0] = bs0[r]; s_ss[p0] = ss0[r]; s_bi[p0] = bi0[r]; s_si[p0] = si0[r];
                const int p1 = p0 + 16;
                s_bs[p1] = bs1[r]; s_ss[p1] = ss1[r]; s_bi[p1] = bi1[r]; s_si[p1] = si1[r];
            }
        }
        // wave-internal LDS RAW below: compiler orders via lgkmcnt (same wave).

        // ---- fp64 refinement of near-ties, wave-local (lanes 0..31) ----
        if (lane < 32) {
            const int p = wloc + lane;
            int fin = s_bi[p];
            if (s_ss[p] - s_bs[p] < 0.125f) {
                const int i0 = fin, i1 = s_si[p];
                const float* xq = xb + hw0 + p;
                const float* e0 = emb + (size_t)i0 * D;
                const float* e1 = emb + (size_t)i1 * D;
                double sa = 0.0, sb = 0.0;
                for (int d = 0; d < D; ++d) {
                    double xvv = (double)xq[(size_t)d * HW];
                    double ev0 = (double)e0[d];
                    double ev1 = (double)e1[d];
                    sa += ev0 * (ev0 - 2.0 * xvv);
                    sb += ev1 * (ev1 - 2.0 * xvv);
                }
                if (sb < sa || (sb == sa && i1 < i0)) fin = i1;
            }
            s_idx[p] = fin;
        }

        // ---- quant writes for own 32 pixels (overlaps writer-wave zero stream) ----
        {
            const int p   = lane & 31;
            const int ch0 = (lane >> 5) * 32;
            const int id  = s_idx[wloc + p];
            const float* ev = emb + (size_t)id * D;
            float* qb = quant + (size_t)b * D * HW + hw0 + wloc + p;
            #pragma unroll
            for (int j = 0; j < 32; ++j)
                qb[(size_t)(ch0 + j) * HW] = ev[ch0 + j];
        }
        __syncthreads();                            // publish s_idx to writer waves
    } else {
        // ================= WRITER WAVES (pure store stream) =================
        const int wv = wave - 2;                    // 0/1: owns 32 one-hot rows
        float4* encb = (float4*)(enc + (size_t)(pixbase + wv * 32) * K);
        float4 z = {0.f, 0.f, 0.f, 0.f};
        #pragma unroll 8
        for (int i = 0; i < 64; ++i)                // 32 rows * 2KB = 64KB
            encb[i * 64 + lane] = z;
        __syncthreads();                            // drains zeros; s_idx ready
        if (lane < 32) {
            const int p = wv * 32 + lane;
            enc[(size_t)(pixbase + p) * K + s_idx[p]] = 1.0f;  // same wave as zeros
        }
    }
}

extern "C" void kernel_launch(void* const* d_in, const int* in_sizes, int n_in,
                              void* d_out, int out_size, void* d_ws, size_t ws_size,
                              hipStream_t stream)
{
    const float* x   = (const float*)d_in[0];
    const float* emb = (const float*)d_in[1];
    float* enc   = (float*)d_out;
    float* quant = (float*)d_out + (size_t)N * K;

    short* ebuf = (short*)d_ws;                          // 128 KB frag-ordered hi/lo
    float* esq  = (float*)(ebuf + (size_t)K * D * 2);    // 2 KB

    hipLaunchKernelGGL(vq_prep, dim3(K * D / 4 / TPB), dim3(TPB), 0, stream,
                       emb, ebuf, esq);
    hipLaunchKernelGGL(vq_main, dim3(N / PIXB), dim3(TPB), 0, stream,
                       x, emb, ebuf, esq, enc, quant);
}

// Round 6
// 52.801 us; speedup vs baseline: 1.3033x; 1.3033x over previous
//
#include <hip/hip_runtime.h>

// VQ nearest-codebook: x [16,64,64,64] NCHW fp32, emb [512,64] fp32.
// out = concat(one_hot [65536,512] f32, quantized [16,64,64,64] f32).
//
// Round-6:
//   prep: emb -> hi/lo bf16 in conflict-free frag order
//         [chunk][sec][tile][g][cl][8bf16] + e_sq   (sec: hi0,hi1,lo0,lo1)
//         => ds_read_b128 phase groups (16 lanes) read 256B contiguous.
//   main: PIXB=64, grid=1024, 4 blocks/CU (16 waves/CU). K split across
//         wave pairs (kh), 2 A-tiles per wave. Per chunk: reg-stage 32KB ->
//         LDS -> barrier -> fire 32KB one-hot zero-slice (stores drain under
//         the LDS/MFMA compute; end-barrier vmcnt(0) is the overlap point)
//         -> compute 4 tiles -> prefetch next chunk regs -> barrier.
//         Tail: shfl top-2 merge, cross-wave combine, fp64 tie refine,
//         1.0 scatter + quant writes.

constexpr int D    = 64;
constexpr int K    = 512;
constexpr int N    = 65536;
constexpr int HW   = 4096;
constexpr int TPB  = 256;
constexpr int PIXB = 64;
constexpr int NCHUNK = 4;            // 128 codes per chunk

typedef __attribute__((ext_vector_type(8))) short bf16x8;
typedef __attribute__((ext_vector_type(4))) short short4v;
typedef __attribute__((ext_vector_type(4))) float f32x4;

__device__ inline unsigned short f2bf(float f) {           // RNE f32->bf16
    unsigned u = __builtin_bit_cast(unsigned, f);
    unsigned r = u + 0x7fffu + ((u >> 16) & 1u);
    return (unsigned short)(r >> 16);
}
__device__ inline float bf2f(unsigned short h) {
    unsigned u = ((unsigned)h) << 16;
    return __builtin_bit_cast(float, u);
}

// cheap top-2 update (scores strictly ordered; ties keep earlier code)
__device__ inline void top2u(float s, int code, float& bs, float& ss, int& bi, int& si) {
    bool c1 = s < bs;
    bool c2 = s < ss;
    float mx = fmaxf(bs, s);
    bs = fminf(bs, s);
    ss = fminf(ss, mx);
    si = c1 ? bi : (c2 ? code : si);
    bi = c1 ? code : bi;
}
// insert with explicit index tie-break (for cross-lane/cross-wave merges)
__device__ inline void top2_ins(float os, int oi, float& bs, float& ss, int& bi, int& si) {
    bool c1 = (os < bs) || (os == bs && oi < bi);
    bool c2 = (os < ss) || (os == ss && oi < si);
    ss = c1 ? bs : (c2 ? os : ss);
    si = c1 ? bi : (c2 ? oi : si);
    bs = c1 ? os : bs;
    bi = c1 ? oi : bi;
}

// ---------------- prep: emb -> frag-ordered hi/lo bf16 + e_sq ----------------
// ebuf shorts: chunk*16384 + sec*4096 + tile*512 + g*128 + cl*8 + j
__global__ __launch_bounds__(TPB) void vq_prep(
    const float* __restrict__ emb, short* __restrict__ ebuf, float* __restrict__ esq)
{
    const int t    = blockIdx.x * TPB + threadIdx.x;   // 8192 threads
    const int code = t >> 4;
    const int q    = t & 15;
    const int d0   = q * 4;
    float4 f = ((const float4*)emb)[t];
    unsigned short h0 = f2bf(f.x), h1 = f2bf(f.y), h2 = f2bf(f.z), h3 = f2bf(f.w);
    short4v hv = { (short)h0, (short)h1, (short)h2, (short)h3 };
    short4v lv = { (short)f2bf(f.x - bf2f(h0)), (short)f2bf(f.y - bf2f(h1)),
                   (short)f2bf(f.z - bf2f(h2)), (short)f2bf(f.w - bf2f(h3)) };
    const int chunk = code >> 7, cc = code & 127, tile = cc >> 4, cl = cc & 15;
    const int g = (d0 & 31) >> 3, j0 = d0 & 7, secH = (d0 >= 32) ? 1 : 0;
    const int base = chunk * 16384 + tile * 512 + g * 128 + cl * 8 + j0;
    *(short4v*)&ebuf[base + secH * 4096]       = hv;
    *(short4v*)&ebuf[base + (2 + secH) * 4096] = lv;
    float pe = f.x * f.x + f.y * f.y + f.z * f.z + f.w * f.w;
    pe += __shfl_xor(pe, 1);
    pe += __shfl_xor(pe, 2);
    pe += __shfl_xor(pe, 4);
    pe += __shfl_xor(pe, 8);
    if (q == 0) esq[code] = pe;
}

// ---------------- main ----------------
__global__ __launch_bounds__(TPB, 4) void vq_main(
    const float* __restrict__ x, const float* __restrict__ emb,
    const short* __restrict__ ebuf, const float* __restrict__ esq,
    float* __restrict__ enc, float* __restrict__ quant)
{
    __shared__ short s_e[16384];                  // 32 KB chunk buffer
    __shared__ float s_tbs[2][PIXB], s_tss[2][PIXB];
    __shared__ int   s_tbi[2][PIXB], s_tsi[2][PIXB];
    __shared__ int   s_idx[PIXB];

    const int tid  = threadIdx.x;
    const int lane = tid & 63;
    const int wave = __builtin_amdgcn_readfirstlane(tid >> 6);
    const int g    = lane >> 4;
    const int cl   = lane & 15;
    const int ph   = wave & 1;                    // pixel half (32 px)
    const int kh   = wave >> 1;                   // K half (tiles 0-3 / 4-7 per chunk)
    const int wloc = ph * 32;

    const int pixbase = blockIdx.x * PIXB;
    const int b   = pixbase >> 12;
    const int hw0 = pixbase & (HW - 1);
    const float* xb = x + (size_t)b * D * HW;

    // ---- x loads for two A-tiles (coalesced 64B segments) ----
    float xv0[16], xv1[16];
    #pragma unroll
    for (int j = 0; j < 8; ++j) {
        const size_t o0 = (size_t)(g * 8 + j) * HW + hw0 + wloc + cl;
        const size_t o1 = (size_t)(32 + g * 8 + j) * HW + hw0 + wloc + cl;
        xv0[j]     = xb[o0];       xv0[8 + j] = xb[o1];
        xv1[j]     = xb[o0 + 16];  xv1[8 + j] = xb[o1 + 16];
    }
    bf16x8 a0h0, a0h1, a0l0, a0l1, a1h0, a1h1, a1l0, a1l1;
    #pragma unroll
    for (int j = 0; j < 8; ++j) {
        unsigned short h;
        h = f2bf(xv0[j]);     a0h0[j] = (short)h; a0l0[j] = (short)f2bf(xv0[j]     - bf2f(h));
        h = f2bf(xv0[8 + j]); a0h1[j] = (short)h; a0l1[j] = (short)f2bf(xv0[8 + j] - bf2f(h));
        h = f2bf(xv1[j]);     a1h0[j] = (short)h; a1l0[j] = (short)f2bf(xv1[j]     - bf2f(h));
        h = f2bf(xv1[8 + j]); a1h1[j] = (short)h; a1l1[j] = (short)f2bf(xv1[8 + j] - bf2f(h));
    }

    float bs0[4], ss0[4], bs1[4], ss1[4];
    int   bi0[4], si0[4], bi1[4], si1[4];
    #pragma unroll
    for (int r = 0; r < 4; ++r) {
        bs0[r] = ss0[r] = bs1[r] = ss1[r] = 3.4e38f;
        bi0[r] = si0[r] = bi1[r] = si1[r] = 0x7fffffff;
    }

    const bf16x8* gsrc = (const bf16x8*)ebuf;     // 16B units; chunk stride 2048
    bf16x8* se8 = (bf16x8*)s_e;
    float4* encb4 = (float4*)(enc + (size_t)pixbase * K);
    const float4 z4 = {0.f, 0.f, 0.f, 0.f};

    // prefetch chunk 0 into regs
    bf16x8 stg[8];
    #pragma unroll
    for (int i = 0; i < 8; ++i) stg[i] = gsrc[i * 256 + tid];

    for (int chunk = 0; chunk < NCHUNK; ++chunk) {
        // ---- stage regs -> LDS (conflict-free contiguous b128) ----
        #pragma unroll
        for (int i = 0; i < 8; ++i) se8[i * 256 + tid] = stg[i];
        __syncthreads();

        // ---- fire this interval's one-hot zero slice (32 KB/block) ----
        #pragma unroll
        for (int it = 0; it < 8; ++it)
            encb4[chunk * 2048 + it * 256 + tid] = z4;

        // ---- e_sq for this wave's 4 tiles ----
        float eqc[4];
        #pragma unroll
        for (int tt = 0; tt < 4; ++tt)
            eqc[tt] = esq[chunk * 128 + (kh * 4 + tt) * 16 + cl];

        // ---- compute 4 tiles (pure LDS/MFMA/VALU; stores drain underneath) ----
        #pragma unroll
        for (int tt = 0; tt < 4; ++tt) {
            const int t8 = kh * 4 + tt;
            const short* pb = s_e + t8 * 512 + g * 128 + cl * 8;
            bf16x8 bh0 = *(const bf16x8*)pb;
            bf16x8 bh1 = *(const bf16x8*)(pb + 4096);
            bf16x8 bl0 = *(const bf16x8*)(pb + 8192);
            bf16x8 bl1 = *(const bf16x8*)(pb + 12288);
            f32x4 c0 = {0.f, 0.f, 0.f, 0.f};
            f32x4 c1 = {0.f, 0.f, 0.f, 0.f};
            c0 = __builtin_amdgcn_mfma_f32_16x16x32_bf16(a0h0, bh0, c0, 0, 0, 0);
            c1 = __builtin_amdgcn_mfma_f32_16x16x32_bf16(a1h0, bh0, c1, 0, 0, 0);
            c0 = __builtin_amdgcn_mfma_f32_16x16x32_bf16(a0h1, bh1, c0, 0, 0, 0);
            c1 = __builtin_amdgcn_mfma_f32_16x16x32_bf16(a1h1, bh1, c1, 0, 0, 0);
            c0 = __builtin_amdgcn_mfma_f32_16x16x32_bf16(a0l0, bh0, c0, 0, 0, 0);
            c1 = __builtin_amdgcn_mfma_f32_16x16x32_bf16(a1l0, bh0, c1, 0, 0, 0);
            c0 = __builtin_amdgcn_mfma_f32_16x16x32_bf16(a0l1, bh1, c0, 0, 0, 0);
            c1 = __builtin_amdgcn_mfma_f32_16x16x32_bf16(a1l1, bh1, c1, 0, 0, 0);
            c0 = __builtin_amdgcn_mfma_f32_16x16x32_bf16(a0h0, bl0, c0, 0, 0, 0);
            c1 = __builtin_amdgcn_mfma_f32_16x16x32_bf16(a1h0, bl0, c1, 0, 0, 0);
            c0 = __builtin_amdgcn_mfma_f32_16x16x32_bf16(a0h1, bl1, c0, 0, 0, 0);
            c1 = __builtin_amdgcn_mfma_f32_16x16x32_bf16(a1h1, bl1, c1, 0, 0, 0);
            const int code = chunk * 128 + t8 * 16 + cl;
            #pragma unroll
            for (int r = 0; r < 4; ++r) {
                top2u(fmaf(-2.0f, c0[r], eqc[tt]), code, bs0[r], ss0[r], bi0[r], si0[r]);
                top2u(fmaf(-2.0f, c1[r], eqc[tt]), code, bs1[r], ss1[r], bi1[r], si1[r]);
            }
        }

        // ---- prefetch next chunk (issued before the drain barrier) ----
        if (chunk + 1 < NCHUNK) {
            #pragma unroll
            for (int i = 0; i < 8; ++i)
                stg[i] = gsrc[(chunk + 1) * 2048 + i * 256 + tid];
        }
        __syncthreads();   // vmcnt(0): zero-slice drained (overlapped compute), LDS safe
    }

    // ---- cross-lane top-2 merge (over cl within each g-group) ----
    #pragma unroll
    for (int r = 0; r < 4; ++r) {
        for (int m = 1; m <= 8; m <<= 1) {
            float obs, oss; int obi, osi;
            obs = __shfl_xor(bs0[r], m); obi = __shfl_xor(bi0[r], m);
            oss = __shfl_xor(ss0[r], m); osi = __shfl_xor(si0[r], m);
            top2_ins(obs, obi, bs0[r], ss0[r], bi0[r], si0[r]);
            top2_ins(oss, osi, bs0[r], ss0[r], bi0[r], si0[r]);
            obs = __shfl_xor(bs1[r], m); obi = __shfl_xor(bi1[r], m);
            oss = __shfl_xor(ss1[r], m); osi = __shfl_xor(si1[r], m);
            top2_ins(obs, obi, bs1[r], ss1[r], bi1[r], si1[r]);
            top2_ins(oss, osi, bs1[r], ss1[r], bi1[r], si1[r]);
        }
    }
    if (cl == 0) {
        #pragma unroll
        for (int r = 0; r < 4; ++r) {
            const int p0 = wloc + g * 4 + r;          // C/D row = (lane>>4)*4+reg
            s_tbs[kh][p0] = bs0[r]; s_tss[kh][p0] = ss0[r];
            s_tbi[kh][p0] = bi0[r]; s_tsi[kh][p0] = si0[r];
            const int p1 = p0 + 16;
            s_tbs[kh][p1] = bs1[r]; s_tss[kh][p1] = ss1[r];
            s_tbi[kh][p1] = bi1[r]; s_tsi[kh][p1] = si1[r];
        }
    }
    __syncthreads();

    // ---- combine K halves + fp64 refinement of near-ties ----
    if (tid < PIXB) {
        float bs = s_tbs[0][tid], ss = s_tss[0][tid];
        int   bi = s_tbi[0][tid], si = s_tsi[0][tid];
        top2_ins(s_tbs[1][tid], s_tbi[1][tid], bs, ss, bi, si);
        top2_ins(s_tss[1][tid], s_tsi[1][tid], bs, ss, bi, si);
        int fin = bi;
        if (ss - bs < 0.125f) {
            const float* xq = xb + hw0 + tid;
            const float* e0 = emb + (size_t)bi * D;
            const float* e1 = emb + (size_t)si * D;
            double sa = 0.0, sb = 0.0;
            for (int d = 0; d < D; ++d) {
                double xvv = (double)xq[(size_t)d * HW];
                double ev0 = (double)e0[d];
                double ev1 = (double)e1[d];
                sa += ev0 * (ev0 - 2.0 * xvv);
                sb += ev1 * (ev1 - 2.0 * xvv);
            }
            if (sb < sa || (sb == sa && si < bi)) fin = si;
        }
        s_idx[tid] = fin;
    }
    __syncthreads();

    // ---- 1.0 scatter (zeros fully drained by barriers above) ----
    if (tid < PIXB)
        enc[(size_t)(pixbase + tid) * K + s_idx[tid]] = 1.0f;

    // ---- quant writes: coalesced per-channel segments ----
    {
        const int p   = tid & 63;
        const int ch0 = (tid >> 6) * 16;
        const int id  = s_idx[p];
        float* qb = quant + (size_t)b * D * HW + hw0 + p;
        #pragma unroll
        for (int j = 0; j < 16; ++j)
            qb[(size_t)(ch0 + j) * HW] = emb[(size_t)id * D + ch0 + j];
    }
}

extern "C" void kernel_launch(void* const* d_in, const int* in_sizes, int n_in,
                              void* d_out, int out_size, void* d_ws, size_t ws_size,
                              hipStream_t stream)
{
    const float* x   = (const float*)d_in[0];
    const float* emb = (const float*)d_in[1];
    float* enc   = (float*)d_out;
    float* quant = (float*)d_out + (size_t)N * K;

    short* ebuf = (short*)d_ws;                          // 128 KB frag-ordered hi/lo
    float* esq  = (float*)(ebuf + (size_t)K * D * 2);    // 2 KB

    hipLaunchKernelGGL(vq_prep, dim3(K * D / 4 / TPB), dim3(TPB), 0, stream,
                       emb, ebuf, esq);
    hipLaunchKernelGGL(vq_main, dim3(N / PIXB), dim3(TPB), 0, stream,
                       x, emb, ebuf, esq, enc, quant);
}